// Round 1
// baseline (658.924 us; speedup 1.0000x reference)
//
#include <hip/hip_runtime.h>

#define N1c 25000
#define N2c 5000
#define Dc 256
#define DOUTc 128
#define EPSc 1e-5f
#define NEGc 0.01f

// ---------------- mask output kernel (mask1 -> d_out tail as 0/1 floats) ----
__global__ void mask_out_kernel(const int* __restrict__ val,
                                const int* __restrict__ ts,
                                const int* __restrict__ time_p,
                                const int* __restrict__ itv_p,
                                int E, float* __restrict__ out) {
    int e = blockIdx.x * blockDim.x + threadIdx.x;
    if (e >= E) return;
    int t0 = *time_p, iv = *itv_p;
    int t = ts[val[e]];
    out[e] = (t >= t0 && t < t0 + iv) ? 1.0f : 0.0f;
}

// ---------------- scatter: one wave per edge, 64 lanes x float4 = 256 dims --
__global__ void scatter_kernel(const float* __restrict__ X,
                               const int* __restrict__ src,
                               const int* __restrict__ dst,
                               const int* __restrict__ val,
                               const int* __restrict__ ts,
                               const int* __restrict__ time_p,
                               const int* __restrict__ itv_p,
                               int E,
                               float* __restrict__ agg,
                               float* __restrict__ deg) {
    int wave = (blockIdx.x * blockDim.x + threadIdx.x) >> 6;
    int lane = threadIdx.x & 63;
    if (wave >= E) return;
    int t0 = *time_p, iv = *itv_p;
    int t = ts[val[wave]];                 // same addr across wave -> broadcast
    if (t < t0 || t >= t0 + iv) return;    // masked edge contributes nothing
    int s = src[wave], d = dst[wave];
    float4 v = *(const float4*)(X + (size_t)s * Dc + lane * 4);
    float* a = agg + (size_t)d * Dc + lane * 4;
    atomicAdd(a + 0, v.x);
    atomicAdd(a + 1, v.y);
    atomicAdd(a + 2, v.z);
    atomicAdd(a + 3, v.w);
    if (lane == 0) atomicAdd(deg + d, 1.0f);
}

// ---------------- normalize: agg[row,:] /= max(deg[row],1) ------------------
__global__ void normalize_kernel(float* __restrict__ agg,
                                 const float* __restrict__ deg, int n) {
    int idx = blockIdx.x * blockDim.x + threadIdx.x;  // one float4 per thread
    int total = n * (Dc / 4);
    if (idx >= total) return;
    int row = idx >> 6;                               // Dc/4 = 64 float4/row
    float inv = 1.0f / fmaxf(deg[row], 1.0f);
    float4* p = (float4*)agg + idx;
    float4 v = *p;
    v.x *= inv; v.y *= inv; v.z *= inv; v.w *= inv;
    *p = v;
}

// ---------------- fused dual GEMM: C = A1@B1 + A2@B2 + bias [, BN+leaky] ----
// K = 256 fixed (lda = 256 for both A's). Tile 64x64, 256 thr, 4x4/thread.
// NOTE: C may alias A1 (each block reads only its own A1 rows, all reads
// complete before the epilogue writes) — so A1/C are NOT __restrict__.
template <bool DO_BN>
__global__ __launch_bounds__(256) void gemm_fused(
    const float* A1, const float* A2,
    const float* __restrict__ B1, const float* __restrict__ B2,
    const float* __restrict__ bias,
    const float* __restrict__ g, const float* __restrict__ bt,
    const float* __restrict__ rm, const float* __restrict__ rv,
    float* C, int M, int N) {
    const int K = 256;
    __shared__ float As[16][68];   // [k][m], pad 64->68 to spread banks
    __shared__ float Bs[16][64];   // [k][n]
    int tid = threadIdx.x;
    int tx = tid & 15, ty = tid >> 4;
    int m0 = blockIdx.y * 64, n0 = blockIdx.x * 64;
    int a_row = tid >> 2;          // 0..63
    int a_k = (tid & 3) * 4;       // 0,4,8,12
    int b_k = tid >> 4;            // 0..15
    int b_n = (tid & 15) * 4;      // 0..60
    float acc[4][4] = {};
    const float* Ap[2] = {A1, A2};
    const float* Bp[2] = {B1, B2};
    for (int half = 0; half < 2; ++half) {
        const float* A = Ap[half];
        const float* B = Bp[half];
        for (int k0 = 0; k0 < K; k0 += 16) {
            float4 av = make_float4(0.f, 0.f, 0.f, 0.f);
            int gm = m0 + a_row;
            if (gm < M) av = *(const float4*)(A + (size_t)gm * K + k0 + a_k);
            float4 bv = *(const float4*)(B + (size_t)(k0 + b_k) * N + n0 + b_n);
            __syncthreads();       // previous iter's LDS reads done
            As[a_k + 0][a_row] = av.x;
            As[a_k + 1][a_row] = av.y;
            As[a_k + 2][a_row] = av.z;
            As[a_k + 3][a_row] = av.w;
            *(float4*)&Bs[b_k][b_n] = bv;
            __syncthreads();
#pragma unroll
            for (int k = 0; k < 16; ++k) {
                float4 a4 = *(const float4*)&As[k][ty * 4];
                float4 b4 = *(const float4*)&Bs[k][tx * 4];
                float ar[4] = {a4.x, a4.y, a4.z, a4.w};
                float br[4] = {b4.x, b4.y, b4.z, b4.w};
#pragma unroll
                for (int i = 0; i < 4; ++i)
#pragma unroll
                    for (int j = 0; j < 4; ++j) acc[i][j] += ar[i] * br[j];
            }
        }
    }
#pragma unroll
    for (int i = 0; i < 4; ++i) {
        int gm = m0 + ty * 4 + i;
        if (gm >= M) continue;
#pragma unroll
        for (int j = 0; j < 4; ++j) {
            int gn = n0 + tx * 4 + j;
            float v = acc[i][j] + bias[gn];
            if (DO_BN) {
                v = (v - rm[gn]) * rsqrtf(rv[gn] + EPSc) * g[gn] + bt[gn];
                v = v >= 0.f ? v : NEGc * v;
            }
            C[(size_t)gm * N + gn] = v;
        }
    }
}

extern "C" void kernel_launch(void* const* d_in, const int* in_sizes, int n_in,
                              void* d_out, int out_size, void* d_ws, size_t ws_size,
                              hipStream_t stream) {
    const float* x    = (const float*)d_in[0];
    const int* src0   = (const int*)d_in[1];
    const int* dst0   = (const int*)d_in[2];
    const int* val0   = (const int*)d_in[3];
    const int* src1   = (const int*)d_in[4];
    const int* dst1   = (const int*)d_in[5];
    const int* val1   = (const int*)d_in[6];
    const int* ts     = (const int*)d_in[7];
    const int* time_p = (const int*)d_in[8];
    const int* itv_p  = (const int*)d_in[9];
    const float* W1l  = (const float*)d_in[10];
    const float* W1r  = (const float*)d_in[11];
    const float* b1   = (const float*)d_in[12];
    const float* g1   = (const float*)d_in[13];
    const float* bt1  = (const float*)d_in[14];
    const float* rm1  = (const float*)d_in[15];
    const float* rv1  = (const float*)d_in[16];
    const float* W2l  = (const float*)d_in[17];
    const float* W2r  = (const float*)d_in[18];
    const float* b2   = (const float*)d_in[19];
    int E0 = in_sizes[1];
    int E1 = in_sizes[4];
    float* out = (float*)d_out;

    // Workspace layout (floats). h aliases agg0 (in-place GEMM1, see note).
    float* agg0 = (float*)d_ws;               // N1*256
    float* deg0 = agg0 + (size_t)N1c * Dc;    // N1
    float* agg1 = deg0 + N1c;                 // N2*256
    float* deg1 = agg1 + (size_t)N2c * Dc;    // N2
    size_t total_f = (size_t)N1c * Dc + N1c + (size_t)N2c * Dc + N2c;
    float* h = agg0;

    hipMemsetAsync(d_ws, 0, total_f * sizeof(float), stream);

    // mask1 -> d_out tail (independent of everything else)
    mask_out_kernel<<<(E1 + 255) / 256, 256, 0, stream>>>(
        val1, ts, time_p, itv_p, E1, out + (size_t)N2c * DOUTc);

    // layer 0: scatter, mean, dual-GEMM + BN + leaky (h written in place of agg0)
    scatter_kernel<<<(E0 + 3) / 4, 256, 0, stream>>>(
        x, src0, dst0, val0, ts, time_p, itv_p, E0, agg0, deg0);
    normalize_kernel<<<(N1c * (Dc / 4) + 255) / 256, 256, 0, stream>>>(agg0, deg0, N1c);
    gemm_fused<true><<<dim3(Dc / 64, (N1c + 63) / 64), 256, 0, stream>>>(
        agg0, x, W1l, W1r, b1, g1, bt1, rm1, rv1, h, N1c, Dc);

    // layer 1: scatter on h, mean, dual-GEMM -> out
    scatter_kernel<<<(E1 + 3) / 4, 256, 0, stream>>>(
        h, src1, dst1, val1, ts, time_p, itv_p, E1, agg1, deg1);
    normalize_kernel<<<(N2c * (Dc / 4) + 255) / 256, 256, 0, stream>>>(agg1, deg1, N2c);
    gemm_fused<false><<<dim3(DOUTc / 64, (N2c + 63) / 64), 256, 0, stream>>>(
        agg1, h, W2l, W2r, b2, nullptr, nullptr, nullptr, nullptr, out, N2c, DOUTc);
}

// Round 2
// 425.451 us; speedup vs baseline: 1.5488x; 1.5488x over previous
//
#include <hip/hip_runtime.h>

#define N1c 25000
#define N2c 5000
#define Dc 256
#define DOUTc 128
#define EPSc 1e-5f
#define NEGc 0.01f

// ---------------- mask output kernel (mask1 -> d_out tail as 0/1 floats) ----
__global__ void mask_out_kernel(const int* __restrict__ val,
                                const int* __restrict__ ts,
                                const int* __restrict__ time_p,
                                const int* __restrict__ itv_p,
                                int E, float* __restrict__ out) {
    int e = blockIdx.x * blockDim.x + threadIdx.x;
    if (e >= E) return;
    int t0 = *time_p, iv = *itv_p;
    int t = ts[val[e]];
    out[e] = (t >= t0 && t < t0 + iv) ? 1.0f : 0.0f;
}

// ---------------- CSR build: count masked edges per dst ---------------------
__global__ void count_kernel(const int* __restrict__ dst,
                             const int* __restrict__ val,
                             const int* __restrict__ ts,
                             const int* __restrict__ time_p,
                             const int* __restrict__ itv_p,
                             int E, int* __restrict__ count) {
    int e = blockIdx.x * blockDim.x + threadIdx.x;
    if (e >= E) return;
    int t0 = *time_p, iv = *itv_p;
    int t = ts[val[e]];
    if (t < t0 || t >= t0 + iv) return;
    atomicAdd(&count[dst[e]], 1);
}

// ---------------- single-block exclusive prefix scan (n up to ~32k) ---------
__global__ __launch_bounds__(1024) void scan_kernel(const int* __restrict__ count,
                                                    int* __restrict__ offsets, int n) {
    __shared__ int buf[1024];
    __shared__ int carry_s;
    int tid = threadIdx.x;
    if (tid == 0) { carry_s = 0; offsets[0] = 0; }
    __syncthreads();
    for (int base = 0; base < n; base += 1024) {
        int i = base + tid;
        buf[tid] = (i < n) ? count[i] : 0;
        __syncthreads();
        // Hillis-Steele inclusive scan
        for (int off = 1; off < 1024; off <<= 1) {
            int t = (tid >= off) ? buf[tid - off] : 0;
            __syncthreads();
            buf[tid] += t;
            __syncthreads();
        }
        int carry = carry_s;
        if (i < n) offsets[i + 1] = carry + buf[tid];
        __syncthreads();                    // everyone read carry_s
        if (tid == 1023) carry_s = carry + buf[1023];
        __syncthreads();                    // update visible before next chunk
    }
}

// ---------------- CSR fill: drop src ids into per-dst slots -----------------
__global__ void fill_kernel(const int* __restrict__ src,
                            const int* __restrict__ dst,
                            const int* __restrict__ val,
                            const int* __restrict__ ts,
                            const int* __restrict__ time_p,
                            const int* __restrict__ itv_p,
                            int E,
                            const int* __restrict__ offsets,
                            int* __restrict__ cursor,
                            int* __restrict__ eidx) {
    int e = blockIdx.x * blockDim.x + threadIdx.x;
    if (e >= E) return;
    int t0 = *time_p, iv = *itv_p;
    int t = ts[val[e]];
    if (t < t0 || t >= t0 + iv) return;
    int d = dst[e];
    int pos = atomicAdd(&cursor[d], 1);
    eidx[offsets[d] + pos] = src[e];
}

// ---------------- gather + mean: one wave per dst row -----------------------
__global__ void gather_kernel(const float* __restrict__ X,
                              const int* __restrict__ offsets,
                              const int* __restrict__ eidx,
                              float* __restrict__ agg, int n) {
    int wave = (blockIdx.x * blockDim.x + threadIdx.x) >> 6;
    int lane = threadIdx.x & 63;
    if (wave >= n) return;
    int s0 = offsets[wave], s1 = offsets[wave + 1];
    float4 acc = make_float4(0.f, 0.f, 0.f, 0.f);
    for (int j = s0; j < s1; ++j) {
        int s = eidx[j];                    // wave-uniform broadcast load
        float4 v = *(const float4*)(X + (size_t)s * Dc + lane * 4);
        acc.x += v.x; acc.y += v.y; acc.z += v.z; acc.w += v.w;
    }
    float inv = 1.0f / fmaxf((float)(s1 - s0), 1.0f);
    acc.x *= inv; acc.y *= inv; acc.z *= inv; acc.w *= inv;
    *(float4*)(agg + (size_t)wave * Dc + lane * 4) = acc;
}

// ---------------- fused dual GEMM: C = A1@B1 + A2@B2 + bias [, BN+leaky] ----
// K = 256 fixed (lda = 256 for both A's). Tile 64x64, 256 thr, 4x4/thread.
// NOTE: C may alias A1 (each block reads only its own A1 rows, all reads
// complete before the epilogue writes) — so A1/C are NOT __restrict__.
template <bool DO_BN>
__global__ __launch_bounds__(256) void gemm_fused(
    const float* A1, const float* A2,
    const float* __restrict__ B1, const float* __restrict__ B2,
    const float* __restrict__ bias,
    const float* __restrict__ g, const float* __restrict__ bt,
    const float* __restrict__ rm, const float* __restrict__ rv,
    float* C, int M, int N) {
    const int K = 256;
    __shared__ float As[16][68];   // [k][m], pad 64->68 to spread banks
    __shared__ float Bs[16][64];   // [k][n]
    int tid = threadIdx.x;
    int tx = tid & 15, ty = tid >> 4;
    int m0 = blockIdx.y * 64, n0 = blockIdx.x * 64;
    int a_row = tid >> 2;          // 0..63
    int a_k = (tid & 3) * 4;       // 0,4,8,12
    int b_k = tid >> 4;            // 0..15
    int b_n = (tid & 15) * 4;      // 0..60
    float acc[4][4] = {};
    const float* Ap[2] = {A1, A2};
    const float* Bp[2] = {B1, B2};
    for (int half = 0; half < 2; ++half) {
        const float* A = Ap[half];
        const float* B = Bp[half];
        for (int k0 = 0; k0 < K; k0 += 16) {
            float4 av = make_float4(0.f, 0.f, 0.f, 0.f);
            int gm = m0 + a_row;
            if (gm < M) av = *(const float4*)(A + (size_t)gm * K + k0 + a_k);
            float4 bv = *(const float4*)(B + (size_t)(k0 + b_k) * N + n0 + b_n);
            __syncthreads();       // previous iter's LDS reads done
            As[a_k + 0][a_row] = av.x;
            As[a_k + 1][a_row] = av.y;
            As[a_k + 2][a_row] = av.z;
            As[a_k + 3][a_row] = av.w;
            *(float4*)&Bs[b_k][b_n] = bv;
            __syncthreads();
#pragma unroll
            for (int k = 0; k < 16; ++k) {
                float4 a4 = *(const float4*)&As[k][ty * 4];
                float4 b4 = *(const float4*)&Bs[k][tx * 4];
                float ar[4] = {a4.x, a4.y, a4.z, a4.w};
                float br[4] = {b4.x, b4.y, b4.z, b4.w};
#pragma unroll
                for (int i = 0; i < 4; ++i)
#pragma unroll
                    for (int j = 0; j < 4; ++j) acc[i][j] += ar[i] * br[j];
            }
        }
    }
#pragma unroll
    for (int i = 0; i < 4; ++i) {
        int gm = m0 + ty * 4 + i;
        if (gm >= M) continue;
#pragma unroll
        for (int j = 0; j < 4; ++j) {
            int gn = n0 + tx * 4 + j;
            float v = acc[i][j] + bias[gn];
            if (DO_BN) {
                v = (v - rm[gn]) * rsqrtf(rv[gn] + EPSc) * g[gn] + bt[gn];
                v = v >= 0.f ? v : NEGc * v;
            }
            C[(size_t)gm * N + gn] = v;
        }
    }
}

extern "C" void kernel_launch(void* const* d_in, const int* in_sizes, int n_in,
                              void* d_out, int out_size, void* d_ws, size_t ws_size,
                              hipStream_t stream) {
    const float* x    = (const float*)d_in[0];
    const int* src0   = (const int*)d_in[1];
    const int* dst0   = (const int*)d_in[2];
    const int* val0   = (const int*)d_in[3];
    const int* src1   = (const int*)d_in[4];
    const int* dst1   = (const int*)d_in[5];
    const int* val1   = (const int*)d_in[6];
    const int* ts     = (const int*)d_in[7];
    const int* time_p = (const int*)d_in[8];
    const int* itv_p  = (const int*)d_in[9];
    const float* W1l  = (const float*)d_in[10];
    const float* W1r  = (const float*)d_in[11];
    const float* b1   = (const float*)d_in[12];
    const float* g1   = (const float*)d_in[13];
    const float* bt1  = (const float*)d_in[14];
    const float* rm1  = (const float*)d_in[15];
    const float* rv1  = (const float*)d_in[16];
    const float* W2l  = (const float*)d_in[17];
    const float* W2r  = (const float*)d_in[18];
    const float* b2   = (const float*)d_in[19];
    int E0 = in_sizes[1];
    int E1 = in_sizes[4];
    float* out = (float*)d_out;

    // ---- workspace layout ----
    float* agg0 = (float*)d_ws;                       // N1*256 floats (aliased as h)
    float* agg1 = agg0 + (size_t)N1c * Dc;            // N2*256 floats
    int* ip     = (int*)(agg1 + (size_t)N2c * Dc);
    int* count0   = ip;              ip += N1c;       // -- zeroed region start
    int* cursor0  = ip;              ip += N1c;
    int* count1   = ip;              ip += N2c;
    int* cursor1  = ip;              ip += N2c;       // -- zeroed region end
    int* offsets0 = ip;              ip += N1c + 1;
    int* offsets1 = ip;              ip += N2c + 1;
    int* eidx0    = ip;              ip += E0;
    int* eidx1    = ip;              ip += E1;
    float* h = agg0;                                  // gemm1 output in-place

    hipMemsetAsync(count0, 0, (size_t)(2 * N1c + 2 * N2c) * sizeof(int), stream);

    // mask1 -> d_out tail (independent of everything else)
    mask_out_kernel<<<(E1 + 255) / 256, 256, 0, stream>>>(
        val1, ts, time_p, itv_p, E1, out + (size_t)N2c * DOUTc);

    // ---- layer 0: CSR build + gather-mean + dual-GEMM + BN + leaky ----
    count_kernel<<<(E0 + 255) / 256, 256, 0, stream>>>(
        dst0, val0, ts, time_p, itv_p, E0, count0);
    scan_kernel<<<1, 1024, 0, stream>>>(count0, offsets0, N1c);
    fill_kernel<<<(E0 + 255) / 256, 256, 0, stream>>>(
        src0, dst0, val0, ts, time_p, itv_p, E0, offsets0, cursor0, eidx0);
    gather_kernel<<<(N1c + 3) / 4, 256, 0, stream>>>(x, offsets0, eidx0, agg0, N1c);
    gemm_fused<true><<<dim3(Dc / 64, (N1c + 63) / 64), 256, 0, stream>>>(
        agg0, x, W1l, W1r, b1, g1, bt1, rm1, rv1, h, N1c, Dc);

    // ---- layer 1: CSR build + gather-mean + dual-GEMM -> out ----
    count_kernel<<<(E1 + 255) / 256, 256, 0, stream>>>(
        dst1, val1, ts, time_p, itv_p, E1, count1);
    scan_kernel<<<1, 1024, 0, stream>>>(count1, offsets1, N2c);
    fill_kernel<<<(E1 + 255) / 256, 256, 0, stream>>>(
        src1, dst1, val1, ts, time_p, itv_p, E1, offsets1, cursor1, eidx1);
    gather_kernel<<<(N2c + 3) / 4, 256, 0, stream>>>(h, offsets1, eidx1, agg1, N2c);
    gemm_fused<false><<<dim3(DOUTc / 64, (N2c + 63) / 64), 256, 0, stream>>>(
        agg1, h, W2l, W2r, b2, nullptr, nullptr, nullptr, nullptr, out, N2c, DOUTc);
}

// Round 3
// 306.167 us; speedup vs baseline: 2.1522x; 1.3896x over previous
//
#include <hip/hip_runtime.h>

#define N1c 25000
#define N2c 5000
#define Dc 256
#define DOUTc 128
#define EPSc 1e-5f
#define NEGc 0.01f

typedef __attribute__((ext_vector_type(8))) short short8;
typedef __attribute__((ext_vector_type(4))) float f32x4;

__device__ __forceinline__ ushort f2bf(float f) {
    unsigned u = __float_as_uint(f);
    u += 0x7fffu + ((u >> 16) & 1u);          // round-to-nearest-even
    return (ushort)(u >> 16);
}
__device__ __forceinline__ float bf2f(ushort u) {
    return __uint_as_float(((unsigned)u) << 16);
}

// ---------------- mask output kernel (mask1 -> d_out tail as 0/1 floats) ----
__global__ void mask_out_kernel(const int* __restrict__ val,
                                const int* __restrict__ ts,
                                const int* __restrict__ time_p,
                                const int* __restrict__ itv_p,
                                int E, float* __restrict__ out) {
    int e = blockIdx.x * blockDim.x + threadIdx.x;
    if (e >= E) return;
    int t0 = *time_p, iv = *itv_p;
    int t = ts[val[e]];
    out[e] = (t >= t0 && t < t0 + iv) ? 1.0f : 0.0f;
}

// ---------------- CSR build: count masked edges per dst ---------------------
__global__ void count_kernel(const int* __restrict__ dst,
                             const int* __restrict__ val,
                             const int* __restrict__ ts,
                             const int* __restrict__ time_p,
                             const int* __restrict__ itv_p,
                             int E, int* __restrict__ count) {
    int e = blockIdx.x * blockDim.x + threadIdx.x;
    if (e >= E) return;
    int t0 = *time_p, iv = *itv_p;
    int t = ts[val[e]];
    if (t < t0 || t >= t0 + iv) return;
    atomicAdd(&count[dst[e]], 1);
}

// ---------------- fast single-block scan: CH elems/thread + block scan ------
template <int CH>
__global__ __launch_bounds__(1024) void scan_kernel(const int* __restrict__ count,
                                                    int* __restrict__ offsets, int n) {
    __shared__ int sums[1024];
    int t = threadIdx.x;
    int v[CH];
    int base = t * CH;
    int run = 0;
#pragma unroll
    for (int i = 0; i < CH; ++i) {
        int idx = base + i;
        int c = (idx < n) ? count[idx] : 0;
        run += c;
        v[i] = run;                           // inclusive within thread
    }
    sums[t] = run;
    __syncthreads();
    for (int off = 1; off < 1024; off <<= 1) {
        int x = (t >= off) ? sums[t - off] : 0;
        __syncthreads();
        sums[t] += x;
        __syncthreads();
    }
    int pre = (t == 0) ? 0 : sums[t - 1];
    if (t == 0) offsets[0] = 0;
#pragma unroll
    for (int i = 0; i < CH; ++i) {
        int idx = base + i;
        if (idx < n) offsets[idx + 1] = pre + v[i];
    }
}

// ---------------- CSR fill: drop src ids into per-dst slots -----------------
__global__ void fill_kernel(const int* __restrict__ src,
                            const int* __restrict__ dst,
                            const int* __restrict__ val,
                            const int* __restrict__ ts,
                            const int* __restrict__ time_p,
                            const int* __restrict__ itv_p,
                            int E,
                            const int* __restrict__ offsets,
                            int* __restrict__ cursor,
                            int* __restrict__ eidx) {
    int e = blockIdx.x * blockDim.x + threadIdx.x;
    if (e >= E) return;
    int t0 = *time_p, iv = *itv_p;
    int t = ts[val[e]];
    if (t < t0 || t >= t0 + iv) return;
    int d = dst[e];
    int pos = atomicAdd(&cursor[d], 1);
    eidx[offsets[d] + pos] = src[e];
}

// ---------------- gather + mean (fp32 src -> bf16 agg) ----------------------
__global__ void gather_f32(const float* __restrict__ X,
                           const int* __restrict__ off,
                           const int* __restrict__ eidx,
                           ushort* __restrict__ agg, int n) {
    int wave = (blockIdx.x * blockDim.x + threadIdx.x) >> 6;
    int lane = threadIdx.x & 63;
    if (wave >= n) return;
    int s0 = off[wave], s1 = off[wave + 1];
    float4 acc = make_float4(0.f, 0.f, 0.f, 0.f);
    for (int j = s0; j < s1; ++j) {
        int s = eidx[j];
        float4 v = *(const float4*)(X + (size_t)s * Dc + lane * 4);
        acc.x += v.x; acc.y += v.y; acc.z += v.z; acc.w += v.w;
    }
    float inv = 1.0f / fmaxf((float)(s1 - s0), 1.0f);
    ushort4 o;
    o.x = f2bf(acc.x * inv); o.y = f2bf(acc.y * inv);
    o.z = f2bf(acc.z * inv); o.w = f2bf(acc.w * inv);
    *(ushort4*)(agg + (size_t)wave * Dc + lane * 4) = o;
}

// ---------------- gather + mean (bf16 src -> bf16 agg) ----------------------
__global__ void gather_bf16(const ushort* __restrict__ H,
                            const int* __restrict__ off,
                            const int* __restrict__ eidx,
                            ushort* __restrict__ agg, int n) {
    int wave = (blockIdx.x * blockDim.x + threadIdx.x) >> 6;
    int lane = threadIdx.x & 63;
    if (wave >= n) return;
    int s0 = off[wave], s1 = off[wave + 1];
    float4 acc = make_float4(0.f, 0.f, 0.f, 0.f);
    for (int j = s0; j < s1; ++j) {
        int s = eidx[j];
        ushort4 v = *(const ushort4*)(H + (size_t)s * Dc + lane * 4);
        acc.x += bf2f(v.x); acc.y += bf2f(v.y);
        acc.z += bf2f(v.z); acc.w += bf2f(v.w);
    }
    float inv = 1.0f / fmaxf((float)(s1 - s0), 1.0f);
    ushort4 o;
    o.x = f2bf(acc.x * inv); o.y = f2bf(acc.y * inv);
    o.z = f2bf(acc.z * inv); o.w = f2bf(acc.w * inv);
    *(ushort4*)(agg + (size_t)wave * Dc + lane * 4) = o;
}

// ---------------- x[:N1] fp32 -> bf16 ---------------------------------------
__global__ void conv_x_kernel(const float* __restrict__ x,
                              ushort* __restrict__ xb, int n4) {
    int i = blockIdx.x * blockDim.x + threadIdx.x;
    if (i >= n4) return;
    float4 v = ((const float4*)x)[i];
    ushort4 o;
    o.x = f2bf(v.x); o.y = f2bf(v.y); o.z = f2bf(v.z); o.w = f2bf(v.w);
    ((ushort4*)xb)[i] = o;
}

// ---------------- W [256][N] fp32 x2 -> Bt [N][512] bf16 (transposed) -------
__global__ void prep_b(const float* __restrict__ Wl, const float* __restrict__ Wr,
                       int N, ushort* __restrict__ Bt) {
    int k = blockIdx.x;          // 0..255
    int n = threadIdx.x;         // 0..N-1
    Bt[(size_t)n * 512 + k]       = f2bf(Wl[(size_t)k * N + n]);
    Bt[(size_t)n * 512 + 256 + k] = f2bf(Wr[(size_t)k * N + n]);
}

// ---------------- bf16 MFMA GEMM: C = [Alo|Ahi] @ Bt^T + bias [,BN+leaky] ---
// A halves: [M][256] bf16 each (K = 512 total). Bt: [N][512] bf16 (n-major).
// Block = 128 thr (2 waves), tile BM=64 x BN=128, BK=32.
// Wave w owns rows m0+32w..+31 as two 16-row groups sharing each B-frag.
// VARIANT 0: N=256, out = bf16 h[M][256], BN+leaky epilogue.
// VARIANT 1: N=128, out = fp32 [M][128], bias only.
template <int VARIANT>
__global__ __launch_bounds__(128) void gemm_mfma(
    const ushort* __restrict__ Alo, const ushort* __restrict__ Ahi,
    const ushort* __restrict__ Bt,
    const float* __restrict__ bias,
    const float* __restrict__ g, const float* __restrict__ bt,
    const float* __restrict__ rm, const float* __restrict__ rv,
    void* __restrict__ Cout, int M) {
    __shared__ ushort As[64][40];     // +8 pad: row stride 80 B = 20 banks
    __shared__ ushort Bs[128][40];
    int tid = threadIdx.x;
    int wave = tid >> 6, lane = tid & 63;
    int quad = lane >> 4, l16 = lane & 15;
    int m0 = blockIdx.y * 64, n0 = blockIdx.x * 128;
    f32x4 acc[2][8] = {};
    int ar = tid >> 1;                // A stage: row 0..63
    int ak = (tid & 1) * 16;          // 16 bf16 per thread
    int bn = tid;                     // B stage: one row per thread
    for (int k0 = 0; k0 < 512; k0 += 32) {
        const ushort* Ag = (k0 < 256)
            ? (Alo + (size_t)(m0 + ar) * Dc + k0 + ak)
            : (Ahi + (size_t)(m0 + ar) * Dc + (k0 - 256) + ak);
        uint4 a0 = make_uint4(0, 0, 0, 0), a1 = make_uint4(0, 0, 0, 0);
        if (m0 + ar < M) {
            a0 = *(const uint4*)Ag;
            a1 = *(const uint4*)(Ag + 8);
        }
        const ushort* Bg = Bt + (size_t)(n0 + bn) * 512 + k0;
        uint4 b0 = *(const uint4*)(Bg + 0);
        uint4 b1 = *(const uint4*)(Bg + 8);
        uint4 b2 = *(const uint4*)(Bg + 16);
        uint4 b3 = *(const uint4*)(Bg + 24);
        __syncthreads();              // prior iter's LDS reads done
        *(uint4*)&As[ar][ak] = a0;
        *(uint4*)&As[ar][ak + 8] = a1;
        *(uint4*)&Bs[bn][0] = b0;
        *(uint4*)&Bs[bn][8] = b1;
        *(uint4*)&Bs[bn][16] = b2;
        *(uint4*)&Bs[bn][24] = b3;
        __syncthreads();
        short8 af0 = *(const short8*)&As[wave * 32 + l16][quad * 8];
        short8 af1 = *(const short8*)&As[wave * 32 + 16 + l16][quad * 8];
#pragma unroll
        for (int j = 0; j < 8; ++j) {
            short8 bf = *(const short8*)&Bs[j * 16 + l16][quad * 8];
            acc[0][j] = __builtin_amdgcn_mfma_f32_16x16x32_bf16(af0, bf, acc[0][j], 0, 0, 0);
            acc[1][j] = __builtin_amdgcn_mfma_f32_16x16x32_bf16(af1, bf, acc[1][j], 0, 0, 0);
        }
    }
    // epilogue: C/D layout col=lane&15, row=quad*4+reg
#pragma unroll
    for (int grp = 0; grp < 2; ++grp) {
#pragma unroll
        for (int j = 0; j < 8; ++j) {
            int gn = n0 + j * 16 + l16;
            float sc = 1.f, sh = bias[gn];
            if (VARIANT == 0) {
                float s = g[gn] * rsqrtf(rv[gn] + EPSc);
                sh = (bias[gn] - rm[gn]) * s + bt[gn];
                sc = s;
            }
            int gmb = m0 + wave * 32 + grp * 16 + quad * 4;
#pragma unroll
            for (int r = 0; r < 4; ++r) {
                int gm = gmb + r;
                if (gm >= M) continue;
                float v = acc[grp][j][r];
                if (VARIANT == 0) {
                    v = v * sc + sh;
                    v = v >= 0.f ? v : NEGc * v;
                    ((ushort*)Cout)[(size_t)gm * Dc + gn] = f2bf(v);
                } else {
                    ((float*)Cout)[(size_t)gm * DOUTc + gn] = v + sh;
                }
            }
        }
    }
}

extern "C" void kernel_launch(void* const* d_in, const int* in_sizes, int n_in,
                              void* d_out, int out_size, void* d_ws, size_t ws_size,
                              hipStream_t stream) {
    const float* x    = (const float*)d_in[0];
    const int* src0   = (const int*)d_in[1];
    const int* dst0   = (const int*)d_in[2];
    const int* val0   = (const int*)d_in[3];
    const int* src1   = (const int*)d_in[4];
    const int* dst1   = (const int*)d_in[5];
    const int* val1   = (const int*)d_in[6];
    const int* ts     = (const int*)d_in[7];
    const int* time_p = (const int*)d_in[8];
    const int* itv_p  = (const int*)d_in[9];
    const float* W1l  = (const float*)d_in[10];
    const float* W1r  = (const float*)d_in[11];
    const float* b1   = (const float*)d_in[12];
    const float* g1   = (const float*)d_in[13];
    const float* bt1  = (const float*)d_in[14];
    const float* rm1  = (const float*)d_in[15];
    const float* rv1  = (const float*)d_in[16];
    const float* W2l  = (const float*)d_in[17];
    const float* W2r  = (const float*)d_in[18];
    const float* b2   = (const float*)d_in[19];
    int E0 = in_sizes[1];
    int E1 = in_sizes[4];
    float* out = (float*)d_out;

    // ---- workspace layout (bf16 tensors first, then int region) ----
    ushort* agg0 = (ushort*)d_ws;                  // [N1][256]
    ushort* xb   = agg0 + (size_t)N1c * Dc;        // [N1][256]
    ushort* h    = xb   + (size_t)N1c * Dc;        // [N1][256]
    ushort* agg1 = h    + (size_t)N1c * Dc;        // [N2][256]
    ushort* Bt1  = agg1 + (size_t)N2c * Dc;        // [256][512]
    ushort* Bt2  = Bt1  + 256 * 512;               // [128][512]
    int* ip      = (int*)(Bt2 + 128 * 512);
    int* count0   = ip;            ip += N1c;      // -- zeroed region start
    int* cursor0  = ip;            ip += N1c;
    int* count1   = ip;            ip += N2c;
    int* cursor1  = ip;            ip += N2c;      // -- zeroed region end
    int* offsets0 = ip;            ip += N1c + 1;
    int* offsets1 = ip;            ip += N2c + 1;
    int* eidx0    = ip;            ip += E0;
    int* eidx1    = ip;            ip += E1;

    hipMemsetAsync(count0, 0, (size_t)(2 * N1c + 2 * N2c) * sizeof(int), stream);

    // independent prep
    mask_out_kernel<<<(E1 + 255) / 256, 256, 0, stream>>>(
        val1, ts, time_p, itv_p, E1, out + (size_t)N2c * DOUTc);
    prep_b<<<256, 256, 0, stream>>>(W1l, W1r, 256, Bt1);
    prep_b<<<256, 128, 0, stream>>>(W2l, W2r, 128, Bt2);
    conv_x_kernel<<<(N1c * 64 + 255) / 256, 256, 0, stream>>>(x, xb, N1c * 64);

    // ---- layer 0 ----
    count_kernel<<<(E0 + 255) / 256, 256, 0, stream>>>(
        dst0, val0, ts, time_p, itv_p, E0, count0);
    scan_kernel<25><<<1, 1024, 0, stream>>>(count0, offsets0, N1c);
    fill_kernel<<<(E0 + 255) / 256, 256, 0, stream>>>(
        src0, dst0, val0, ts, time_p, itv_p, E0, offsets0, cursor0, eidx0);
    gather_f32<<<(N1c + 3) / 4, 256, 0, stream>>>(x, offsets0, eidx0, agg0, N1c);
    gemm_mfma<0><<<dim3(2, (N1c + 63) / 64), 128, 0, stream>>>(
        agg0, xb, Bt1, b1, g1, bt1, rm1, rv1, h, N1c);

    // ---- layer 1 ----
    count_kernel<<<(E1 + 255) / 256, 256, 0, stream>>>(
        dst1, val1, ts, time_p, itv_p, E1, count1);
    scan_kernel<5><<<1, 1024, 0, stream>>>(count1, offsets1, N2c);
    fill_kernel<<<(E1 + 255) / 256, 256, 0, stream>>>(
        src1, dst1, val1, ts, time_p, itv_p, E1, offsets1, cursor1, eidx1);
    gather_bf16<<<(N2c + 3) / 4, 256, 0, stream>>>(h, offsets1, eidx1, agg1, N2c);
    gemm_mfma<1><<<dim3(1, (N2c + 63) / 64), 128, 0, stream>>>(
        agg1, h, Bt2, b2, nullptr, nullptr, nullptr, nullptr, out, N2c);
}